// Round 7
// baseline (374.390 us; speedup 1.0000x reference)
//
#include <hip/hip_runtime.h>

#define IN_C  128
#define OUT_C 256
#define HIMG  56
#define WIMG  56
#define BIMG  32
#define HW    (HIMG * WIMG)     // 3136
#define KW    1152              // 9*128

#define BM    128               // oc per block (blockIdx.y = half)
#define TH    4                 // output rows per block
#define XROWS 6                 // TH + 2 halo
#define XCOLS 58                // 56 + 2 halo (padded NHWC width)
#define NPIXT (XROWS * XCOLS)   // 348 staged pixels
#define XS_SH (NPIXT * 32)      // 11136 shorts = 22272 B per X buffer
#define XCH   (NPIXT * 4)       // 1392 16-B chunks per X buffer
#define NT    36                // 9 taps * 4 icq

#define NX_BYTES 27557888u      // 32*58*58*128*2 padded NHWC bf16

typedef __attribute__((ext_vector_type(8))) short short8;
typedef __attribute__((ext_vector_type(4))) short short4_;
typedef __attribute__((ext_vector_type(4))) float float4_;

__device__ __forceinline__ unsigned short f32_to_bf16_rne(float f) {
    unsigned u = __builtin_bit_cast(unsigned, f);
    u += 0x7FFFu + ((u >> 16) & 1u);
    return (unsigned short)(u >> 16);
}

// async 16B global->LDS (DMA; lands at lds_base + lane*16, counted by vmcnt)
#define ASYNC16(g, l) __builtin_amdgcn_global_load_lds( \
    (const __attribute__((address_space(1))) unsigned int*)(g), \
    (__attribute__((address_space(3))) unsigned int*)(l), 16, 0, 0)

// ---------------------------------------------------------------------------
// Pre-pass 1: x (NCHW fp32) -> zero-padded NHWC bf16 [b][hp 0..57][wp 0..57][c]
// ---------------------------------------------------------------------------
__global__ __launch_bounds__(256) void x_to_nhwc(
    const float* __restrict__ x, unsigned short* __restrict__ nx)
{
    __shared__ unsigned short T[128][58];   // [c][w], pitch 58 (odd dwords -> spread)
    const int b  = blockIdx.x;
    const int hp = blockIdx.y;              // 0..57
    unsigned short* dst = nx + (size_t)(b * 58 + hp) * 58 * 128;

    if (hp == 0 || hp == 57) {
        for (int i = threadIdx.x; i < 58 * 128; i += 256) dst[i] = 0;
        return;
    }
    const int h = hp - 1;
    for (int e = threadIdx.x; e < 128 * 56; e += 256) {
        int c = e / 56, w = e - c * 56;
        T[c][w] = f32_to_bf16_rne(x[(size_t)(b * IN_C + c) * HW + h * WIMG + w]);
    }
    __syncthreads();
    for (int e = threadIdx.x; e < 58 * 128; e += 256) {
        int wp = e >> 7, c = e & 127;
        dst[wp * 128 + c] = (wp == 0 || wp == 57) ? (unsigned short)0 : T[c][wp - 1];
    }
}

// ---------------------------------------------------------------------------
// Pre-pass 2: weights -> [t=icq*9+r][oc 0..255][chunk c 0..3][j 0..7] bf16
// with the LDS XOR chunk swizzle BAKED IN: chunk c of row oc holds data
// chunk c ^ ((oc>>1)&3). A half's per-tap region (128 rows x 64 B = 8 KB) is
// contiguous -> 1 global_load_lds per wave (512 thr), linear LDS dest.
// ---------------------------------------------------------------------------
__global__ __launch_bounds__(256) void repack_w(
    const float* __restrict__ Wk, unsigned short* __restrict__ Wt)
{
    __shared__ float L[8 * KW];             // 36864 B: 8 oc rows of Wk
    const int oc0 = blockIdx.x * 8;
    for (int i = threadIdx.x; i < 8 * KW; i += 256)
        L[i] = Wk[(size_t)oc0 * KW + i];
    __syncthreads();
    // 2304 vec4 stores: e = (((t*8 + oc)*4 + c)*2 + jg)
    for (int e = threadIdx.x; e < 2304; e += 256) {
        int jg = e & 1, c = (e >> 1) & 3, oc = (e >> 3) & 7, t = e >> 6;
        int icq = t / 9, r = t - icq * 9;
        int ocg = oc0 + oc;
        int s   = c ^ ((ocg >> 1) & 3);     // data chunk stored at LDS chunk c
        short4_ v;
        #pragma unroll
        for (int jj = 0; jj < 4; ++jj) {
            int ic = icq * 32 + s * 8 + jg * 4 + jj;
            v[jj] = (short)f32_to_bf16_rne(L[oc * KW + ic * 9 + r]);
        }
        *(short4_*)&Wt[(size_t)(((t * 256 + ocg) * 4 + c) * 8 + jg * 4)] = v;
    }
}

// ---------------------------------------------------------------------------
// Implicit-GEMM conv, R1's proven per-tap schedule RETILED to 512 threads:
//   8 waves x (32 oc x 112 px) -> acc = 56 regs/wave (R2-R6 post-mortem:
//   64x112 tile's 112 acc regs made every pipelined variant spill at the
//   128-arch-reg split). __launch_bounds__(512,4): 2 blocks/CU, 4 waves/SIMD.
//   A quad-buffered (staged 3 taps ahead, 1 DMA instr/wave/tap, wraps mod 36
//   for uniform vmcnt); X double-buffered per icq (3 DMA instrs/wave).
//   Per-tap: wave-local counted vmcnt forces OWN contribution landed, then
//   barrier -> collectively whole tile landed (R1-proven invariant).
// ---------------------------------------------------------------------------
__global__ __launch_bounds__(512, 4) void conv_gemm(
    const unsigned short* __restrict__ nx,   // padded NHWC bf16
    const unsigned short* __restrict__ Wt,   // repacked weights
    const float* __restrict__ bias, float* __restrict__ out)
{
    __shared__ __align__(16) unsigned short As[4 * 4096];   // 32768 B quad buffer
    __shared__ __align__(16) unsigned short Xs[2 * XS_SH];  // 44544 B

    const int tid  = threadIdx.x;
    const int lane = tid & 63;
    const int wid  = tid >> 6;              // 0..7
    const int bx   = blockIdx.x;            // 0..447
    const int b    = bx / 14;
    const int h0   = (bx - b * 14) * TH;
    const int half = blockIdx.y;

    // 8 waves: 4 oc-groups x 2 px-groups; each wave 32(m) x 112(n) = 2x7 tiles
    const int wm = (wid >> 1) * 32;
    const int wn = (wid & 1) * 112;
    const int q  = lane >> 4;

    int lp0[7];
    #pragma unroll
    for (int ni = 0; ni < 7; ++ni) {
        int nl  = wn + ni * 16 + (lane & 15);
        int ht_ = nl / 56;
        int wt_ = nl - ht_ * 56;
        lp0[ni] = (ht_ + 1) * XCOLS + (wt_ + 1);  // tap (0,0) pixel in Xs
    }

    // A DMA: per-lane source addr; wave w stages rows w*16..w*16+15 (1 KB)
    const char* wtc = (const char*)Wt + half * 8192 + wid * 1024 + lane * 16;
    // A read base (shorts): row = wm + (lane&15) (+16 for mi=1, same swizzle)
    const int abase = (wm + (lane & 15)) * 32 + (q ^ ((lane >> 1) & 3)) * 8;

    // X staging: 1392 chunks, 174/wave = 2 full instrs + lane<46 tail (3/wave)
    int xgo[3];
    #pragma unroll
    for (int i = 0; i < 3; ++i) {
        int C = wid * 174 + (i < 2 ? i * 64 + lane : 128 + lane);
        if (i == 2 && lane >= 46) C = wid * 174;   // masked lanes: safe addr
        int p = C >> 2, c = C & 3;
        int row  = p / XCOLS;
        int colw = p - row * XCOLS;
        int s = c ^ ((p >> 1) & 3);
        xgo[i] = ((b * 58 + h0 + row) * 58 + colw) * 256 + s * 16;
    }
    const char* nxc = (const char*)nx;

    float4_ acc[2][7];
    #pragma unroll
    for (int mi = 0; mi < 2; ++mi)
        #pragma unroll
        for (int ni = 0; ni < 7; ++ni) acc[mi][ni] = (float4_)0.0f;

    auto stage_x = [&](int icq1, int buf) {     // 3 DMA instrs per wave
        ASYNC16(nxc + xgo[0] + icq1 * 64, &Xs[buf * XS_SH + (wid * 174) * 8]);
        ASYNC16(nxc + xgo[1] + icq1 * 64, &Xs[buf * XS_SH + (wid * 174 + 64) * 8]);
        if (lane < 46)
            ASYNC16(nxc + xgo[2] + icq1 * 64, &Xs[buf * XS_SH + (wid * 174 + 128) * 8]);
    };
    auto stage_a = [&](int t3, int buf) {       // 1 DMA instr per wave
        ASYNC16(wtc + (size_t)t3 * 16384, &As[buf * 4096 + wid * 512]);
    };

    // prologue: X(0) first (oldest), then A(0..2) -> 6 outstanding per wave
    stage_x(0, 0);
    stage_a(0, 0); stage_a(1, 1); stage_a(2, 2);

    #pragma unroll 1
    for (int icq = 0; icq < 4; ++icq) {
        const unsigned short* Xb = &Xs[(icq & 1) * XS_SH];
        const bool notlast = icq < 3;

        #pragma unroll
        for (int r = 0; r < 9; ++r) {
            // per-wave ledger: in-flight A(t),A(t+1),A(t+2) (+X(icq+1) at
            // r=1..3). Retire own A(t) (and, transitively, older X(icq)):
            if (r >= 1 && r <= 3 && notlast)
                asm volatile("s_waitcnt vmcnt(5)" ::: "memory");
            else
                asm volatile("s_waitcnt vmcnt(2)" ::: "memory");
            __builtin_amdgcn_s_barrier();
            asm volatile("" ::: "memory");      // no LDS reads above barrier

            const int rb   = (icq + r) & 3;     // read buffer (= t mod 4)
            const int doff = (r / 3 - 1) * XCOLS + (r % 3 - 1);  // compile-time

            short8 afr0 = *(const short8*)&As[rb * 4096 + abase];
            short8 afr1 = *(const short8*)&As[rb * 4096 + abase + 512];
            short8 bfr[7];
            #pragma unroll
            for (int ni = 0; ni < 7; ++ni) {
                int lp   = lp0[ni] + doff;
                int slot = q ^ ((lp >> 1) & 3);
                bfr[ni]  = *(const short8*)&Xb[lp * 32 + slot * 8];
            }

            // prefetch A(t+3) (wrap mod 36: dummy but in-bounds, keeps vmcnt
            // ledger uniform; its dest buffer was last read at tap t-1)
            {
                int t3 = icq * 9 + r + 3;
                if (t3 >= NT) t3 -= NT;
                stage_a(t3, (icq + r + 3) & 3);
            }
            if (r == 0 && notlast) stage_x(icq + 1, (icq + 1) & 1);

            __builtin_amdgcn_s_setprio(1);
            #pragma unroll
            for (int ni = 0; ni < 7; ++ni) {
                acc[0][ni] = __builtin_amdgcn_mfma_f32_16x16x32_bf16(
                    afr0, bfr[ni], acc[0][ni], 0, 0, 0);
                acc[1][ni] = __builtin_amdgcn_mfma_f32_16x16x32_bf16(
                    afr1, bfr[ni], acc[1][ni], 0, 0, 0);
            }
            __builtin_amdgcn_s_setprio(0);
        }
    }

    // epilogue: C/D layout col=lane&15, row=(lane>>4)*4+v (m89-verified)
    int outoff[7];
    #pragma unroll
    for (int ni = 0; ni < 7; ++ni) {
        int nl  = wn + ni * 16 + (lane & 15);
        int ht_ = nl / 56;
        int wt_ = nl - ht_ * 56;
        outoff[ni] = (h0 + ht_) * WIMG + wt_;
    }
    const int rowg = (lane >> 4) * 4;
    const int ocb  = half * BM + wm;
    #pragma unroll
    for (int mi = 0; mi < 2; ++mi) {
        #pragma unroll
        for (int v = 0; v < 4; ++v) {
            const int oc = ocb + mi * 16 + rowg + v;
            const float bv = bias[oc];
            float* obase = out + (size_t)(b * OUT_C + oc) * HW;
            #pragma unroll
            for (int ni = 0; ni < 7; ++ni)
                obase[outoff[ni]] = acc[mi][ni][v] + bv;
        }
    }
}

extern "C" void kernel_launch(void* const* d_in, const int* in_sizes, int n_in,
                              void* d_out, int out_size, void* d_ws, size_t ws_size,
                              hipStream_t stream) {
    (void)in_sizes; (void)n_in; (void)out_size; (void)ws_size;
    const float* x    = (const float*)d_in[0];
    const float* Wk   = (const float*)d_in[1];
    const float* bias = (const float*)d_in[2];
    float* out        = (float*)d_out;

    // workspace: [0, NX_BYTES) padded NHWC bf16 ; then 589824 B repacked W
    unsigned short* nx = (unsigned short*)d_ws;
    unsigned short* Wt = (unsigned short*)((char*)d_ws + NX_BYTES);

    x_to_nhwc<<<dim3(BIMG, 58), dim3(256), 0, stream>>>(x, nx);
    repack_w<<<dim3(OUT_C / 8), dim3(256), 0, stream>>>(Wk, Wt);
    conv_gemm<<<dim3(BIMG * (HIMG / TH), OUT_C / BM), dim3(512), 0, stream>>>(nx, Wt, bias, out);
}

// Round 8
// 210.504 us; speedup vs baseline: 1.7785x; 1.7785x over previous
//
#include <hip/hip_runtime.h>

#define IN_C  128
#define OUT_C 256
#define HIMG  56
#define WIMG  56
#define BIMG  32
#define HW    (HIMG * WIMG)     // 3136
#define KW    1152              // 9*128

#define BM    128               // oc per block
#define TH    4                 // output rows per block
#define XROWS 6                 // TH + 2 halo
#define XCOLS 58                // 56 + 2 halo (padded NHWC width)
#define NPIXT (XROWS * XCOLS)   // 348 staged pixels
#define XS_SH (NPIXT * 32)      // 11136 shorts = 22272 B per X buffer
#define XCH   (NPIXT * 4)       // 1392 16-B chunks per X buffer
#define NT    36                // 9 taps * 4 icq

#define NX_BYTES 27557888u      // 32*58*58*128*2 padded NHWC bf16

typedef __attribute__((ext_vector_type(8))) short short8;
typedef __attribute__((ext_vector_type(4))) short short4_;
typedef __attribute__((ext_vector_type(4))) float float4_;

__device__ __forceinline__ unsigned short f32_to_bf16_rne(float f) {
    unsigned u = __builtin_bit_cast(unsigned, f);
    u += 0x7FFFu + ((u >> 16) & 1u);
    return (unsigned short)(u >> 16);
}

// async 16B global->LDS (DMA; lands at lds_base + lane*16, counted by vmcnt)
#define ASYNC16(g, l) __builtin_amdgcn_global_load_lds( \
    (const __attribute__((address_space(1))) unsigned int*)(g), \
    (__attribute__((address_space(3))) unsigned int*)(l), 16, 0, 0)

// ---------------------------------------------------------------------------
// Pre-pass 1: x (NCHW fp32) -> zero-padded NHWC bf16 [b][hp 0..57][wp 0..57][c]
// ---------------------------------------------------------------------------
__global__ __launch_bounds__(256) void x_to_nhwc(
    const float* __restrict__ x, unsigned short* __restrict__ nx)
{
    __shared__ unsigned short T[128][58];   // [c][w], pitch 58 (odd dwords -> spread)
    const int b  = blockIdx.x;
    const int hp = blockIdx.y;              // 0..57
    unsigned short* dst = nx + (size_t)(b * 58 + hp) * 58 * 128;

    if (hp == 0 || hp == 57) {
        for (int i = threadIdx.x; i < 58 * 128; i += 256) dst[i] = 0;
        return;
    }
    const int h = hp - 1;
    for (int e = threadIdx.x; e < 128 * 56; e += 256) {
        int c = e / 56, w = e - c * 56;
        T[c][w] = f32_to_bf16_rne(x[(size_t)(b * IN_C + c) * HW + h * WIMG + w]);
    }
    __syncthreads();
    for (int e = threadIdx.x; e < 58 * 128; e += 256) {
        int wp = e >> 7, c = e & 127;
        dst[wp * 128 + c] = (wp == 0 || wp == 57) ? (unsigned short)0 : T[c][wp - 1];
    }
}

// ---------------------------------------------------------------------------
// Pre-pass 2: weights -> [t=icq*9+r][oc 0..255][chunk c 0..3][j 0..7] bf16
// with the LDS XOR chunk swizzle BAKED IN: chunk c of row oc holds data
// chunk c ^ ((oc>>1)&3). A wave's per-tap region (64 oc rows x 64 B) is one
// contiguous 4 KB span -> 4x global_load_lds, linear LDS dest (rule #21).
// ---------------------------------------------------------------------------
__global__ __launch_bounds__(256) void repack_w(
    const float* __restrict__ Wk, unsigned short* __restrict__ Wt)
{
    __shared__ float L[8 * KW];             // 36864 B: 8 oc rows of Wk
    const int oc0 = blockIdx.x * 8;
    for (int i = threadIdx.x; i < 8 * KW; i += 256)
        L[i] = Wk[(size_t)oc0 * KW + i];
    __syncthreads();
    // 2304 vec4 stores: e = (((t*8 + oc)*4 + c)*2 + jg)
    for (int e = threadIdx.x; e < 2304; e += 256) {
        int jg = e & 1, c = (e >> 1) & 3, oc = (e >> 3) & 7, t = e >> 6;
        int icq = t / 9, r = t - icq * 9;
        int ocg = oc0 + oc;
        int s   = c ^ ((ocg >> 1) & 3);     // data chunk stored at LDS chunk c
        short4_ v;
        #pragma unroll
        for (int jj = 0; jj < 4; ++jj) {
            int ic = icq * 32 + s * 8 + jg * 4 + jj;
            v[jj] = (short)f32_to_bf16_rne(L[oc * KW + ic * 9 + r]);
        }
        *(short4_*)&Wt[(size_t)(((t * 256 + ocg) * 4 + c) * 8 + jg * 4)] = v;
    }
}

// ---------------------------------------------------------------------------
// Implicit-GEMM conv, barrier-per-icq, RUNTIME loops:
//   - R6's memory/sync structure (A per-wave private LDS dbuf via
//     global_load_lds; X cooperative per-icq dbuf; ONE barrier per icq;
//     counted vmcnt, never 0 except the last tap)
//   - but BOTH loops #pragma unroll 1 (R4/R6/R7 post-mortem: the unrolled
//     9-tap body stretches live ranges -> arch-VGPR spill every time; R1's
//     runtime-loop register shape (~104 arch) is the only proven-clean one).
//   - runtime doff via r/3 = (r*11)>>5 (no div), A parity = t&1.
// ---------------------------------------------------------------------------
__global__ __launch_bounds__(256, 2) void conv_gemm(
    const unsigned short* __restrict__ nx,   // padded NHWC bf16
    const unsigned short* __restrict__ Wt,   // repacked weights
    const float* __restrict__ bias, float* __restrict__ out)
{
    __shared__ __align__(16) unsigned short As[4 * 2 * 2048];  // 32768 B, per-wave dbuf
    __shared__ __align__(16) unsigned short Xs[2 * XS_SH];     // 44544 B

    const int tid  = threadIdx.x;
    const int lane = tid & 63;
    const int wid  = tid >> 6;
    const int bx   = blockIdx.x;            // 0..447
    const int b    = bx / 14;
    const int h0   = (bx - b * 14) * TH;
    const int half = blockIdx.y;

    // 4 waves, each owns a 64(m) x 112(n) quadrant: 4x7 MFMA tiles
    const int wm = (wid >> 1) * 64;
    const int wn = (wid & 1) * 112;
    const int q  = lane >> 4;

    int lp0[7];
    #pragma unroll
    for (int ni = 0; ni < 7; ++ni) {
        int nl  = wn + ni * 16 + (lane & 15);
        int ht_ = nl / 56;
        int wt_ = nl - ht_ * 56;
        lp0[ni] = (ht_ + 1) * XCOLS + (wt_ + 1);  // tap (0,0) pixel in Xs
    }

    // A DMA: per-lane global source (swizzle baked in repack), per-wave LDS dest
    const char* wsrc = (const char*)Wt
        + (size_t)(half * BM + wm) * 64 + lane * 16;
    // A read base (shorts): row_local = lane&15 (+ mi*16), chunk = q ^ swz(row)
    const int abase = wid * 4096 + (lane & 15) * 32 + (q ^ ((lane >> 1) & 3)) * 8;

    // X staging chunks (per-wave 348: 5 full + 28-lane tail), source
    // pre-swizzled (rule #21: linear LDS dest + swizzled global source)
    int xgo[6];
    #pragma unroll
    for (int i = 0; i < 6; ++i) {
        int C = wid * 348 + i * 64 + lane;
        if (C >= XCH) C = XCH - 1;          // masked lanes only; keep addr sane
        int p = C >> 2, c = C & 3;
        int row  = p / XCOLS;
        int colw = p - row * XCOLS;
        int s = c ^ ((p >> 1) & 3);
        xgo[i] = ((b * 58 + h0 + row) * 58 + colw) * 256 + s * 16;
    }
    const char* nxc = (const char*)nx;

    float4_ acc[4][7];
    #pragma unroll
    for (int mi = 0; mi < 4; ++mi)
        #pragma unroll
        for (int ni = 0; ni < 7; ++ni) acc[mi][ni] = (float4_)0.0f;

    auto stage_x = [&](int icq1, int bufX1) {   // 6 DMA instrs per wave
        #pragma unroll
        for (int i = 0; i < 5; ++i)
            ASYNC16(nxc + xgo[i] + icq1 * 64,
                    &Xs[bufX1 * XS_SH + (wid * 348 + i * 64) * 8]);
        if (lane < 28)
            ASYNC16(nxc + xgo[5] + icq1 * 64,
                    &Xs[bufX1 * XS_SH + (wid * 348 + 5 * 64) * 8]);
    };
    auto stage_a = [&](const char* src, int dstoff /*shorts*/) {  // 4 DMA instrs
        unsigned short* dst = &As[dstoff];
        ASYNC16(src,        dst);
        ASYNC16(src + 1024, dst + 512);
        ASYNC16(src + 2048, dst + 1024);
        ASYNC16(src + 3072, dst + 1536);
    };

    // prologue: X(0) first (oldest -> first barrier's vmcnt(4) retires it), A(0)
    stage_x(0, 0);
    stage_a(wsrc, wid * 4096);

    #pragma unroll 1
    for (int icq = 0; icq < 4; ++icq) {
        // own X(icq) contribution landed (only A(t) batch may stay in flight);
        // barrier makes it collective.
        asm volatile("s_waitcnt vmcnt(4)" ::: "memory");
        __builtin_amdgcn_s_barrier();
        asm volatile("" ::: "memory");      // no LDS reads hoisted above barrier

        const unsigned short* Xb = &Xs[(icq & 1) * XS_SH];
        const bool notlast = icq < 3;

        #pragma unroll 1
        for (int r = 0; r < 9; ++r) {
            const int t     = icq * 9 + r;
            const int rdiv3 = (r * 11) >> 5;          // r/3 for r in [0,9)
            const int doff  = rdiv3 * 55 + r - 59;    // (r/3-1)*58 + r%3 - 1

            // issue A(t+1) into the other parity; X(icq+1) once per icq
            if (t + 1 < NT)
                stage_a(wsrc + (size_t)(t + 1) * 16384,
                        wid * 4096 + ((t + 1) & 1) * 2048);
            if (r == 2 && notlast) stage_x(icq + 1, (icq + 1) & 1);

            // counted wait: A(t) landed, newer loads stay in flight.
            //   r==2: newer = A(t+1)(4) + X(6) = 10 ; r==3: X(6)+A(t+1)(4) = 10
            //   last tap: drain all. else: newer = A(t+1) = 4.
            if (t == NT - 1)
                asm volatile("s_waitcnt vmcnt(0)"  ::: "memory");
            else if ((r == 2 || r == 3) && notlast)
                asm volatile("s_waitcnt vmcnt(10)" ::: "memory");
            else
                asm volatile("s_waitcnt vmcnt(4)"  ::: "memory");

            short8 afr[4], bfr[7];
            const int aro = abase + (t & 1) * 2048;
            #pragma unroll
            for (int mi = 0; mi < 4; ++mi)
                afr[mi] = *(const short8*)&As[aro + mi * 512];
            #pragma unroll
            for (int ni = 0; ni < 7; ++ni) {
                int lp   = lp0[ni] + doff;
                int slot = q ^ ((lp >> 1) & 3);
                bfr[ni]  = *(const short8*)&Xb[lp * 32 + slot * 8];
            }

            __builtin_amdgcn_s_setprio(1);
            #pragma unroll
            for (int mi = 0; mi < 4; ++mi)
                #pragma unroll
                for (int ni = 0; ni < 7; ++ni)
                    acc[mi][ni] = __builtin_amdgcn_mfma_f32_16x16x32_bf16(
                        afr[mi], bfr[ni], acc[mi][ni], 0, 0, 0);
            __builtin_amdgcn_s_setprio(0);
        }
    }

    // epilogue: C/D layout col=lane&15, row=(lane>>4)*4+v (m89-verified)
    int outoff[7];
    #pragma unroll
    for (int ni = 0; ni < 7; ++ni) {
        int nl  = wn + ni * 16 + (lane & 15);
        int ht_ = nl / 56;
        int wt_ = nl - ht_ * 56;
        outoff[ni] = (h0 + ht_) * WIMG + wt_;
    }
    const int rowg = (lane >> 4) * 4;
    const int oc0  = half * BM;
    #pragma unroll
    for (int mi = 0; mi < 4; ++mi) {
        #pragma unroll
        for (int v = 0; v < 4; ++v) {
            const int oc = oc0 + wm + mi * 16 + rowg + v;
            const float bv = bias[oc];
            float* obase = out + (size_t)(b * OUT_C + oc) * HW;
            #pragma unroll
            for (int ni = 0; ni < 7; ++ni)
                obase[outoff[ni]] = acc[mi][ni][v] + bv;
        }
    }
}

extern "C" void kernel_launch(void* const* d_in, const int* in_sizes, int n_in,
                              void* d_out, int out_size, void* d_ws, size_t ws_size,
                              hipStream_t stream) {
    (void)in_sizes; (void)n_in; (void)out_size; (void)ws_size;
    const float* x    = (const float*)d_in[0];
    const float* Wk   = (const float*)d_in[1];
    const float* bias = (const float*)d_in[2];
    float* out        = (float*)d_out;

    // workspace: [0, NX_BYTES) padded NHWC bf16 ; then 589824 B repacked W
    unsigned short* nx = (unsigned short*)d_ws;
    unsigned short* Wt = (unsigned short*)((char*)d_ws + NX_BYTES);

    x_to_nhwc<<<dim3(BIMG, 58), dim3(256), 0, stream>>>(x, nx);
    repack_w<<<dim3(OUT_C / 8), dim3(256), 0, stream>>>(Wk, Wt);
    conv_gemm<<<dim3(BIMG * (HIMG / TH), OUT_C / BM), dim3(256), 0, stream>>>(nx, Wt, bias, out);
}